// Round 2
// baseline (2819.098 us; speedup 1.0000x reference)
//
#include <hip/hip_runtime.h>
#include <hip/hip_bf16.h>

#define NN 10000
#define NE 320000
#define HD 128
#define NL 6
#define EPSV 1e-5f

__device__ __forceinline__ float relu_(float x){ return fmaxf(x, 0.0f); }

// ---------------- degree / scan / place (CSR build) ----------------

__global__ void k_degree(const int* __restrict__ dst, int* __restrict__ counts){
  int e = blockIdx.x*256 + threadIdx.x;
  if (e < NE) atomicAdd(&counts[dst[e]], 1);
}

__global__ void k_scan(const int* __restrict__ counts, int* __restrict__ offs, float* __restrict__ invc){
  __shared__ int lds[1024];
  __shared__ int base_s;
  int tid = threadIdx.x;
  if (tid==0) base_s = 0;
  __syncthreads();
  for (int start=0; start<NN; start+=1024){
    int i = start+tid;
    int vv = (i<NN)? counts[i] : 0;
    lds[tid]=vv; __syncthreads();
    for (int off=1; off<1024; off<<=1){
      int t = (tid>=off)? lds[tid-off] : 0;
      __syncthreads();
      lds[tid] += t;
      __syncthreads();
    }
    int incl = lds[tid];
    if (i<NN){
      offs[i] = base_s + incl - vv;
      invc[i] = 1.0f / fmaxf((float)vv, 1.0f);
    }
    __syncthreads();
    if (tid==1023) base_s += lds[1023];
    __syncthreads();
  }
  if (tid==0) offs[NN] = base_s;
}

__global__ void k_place(const int* __restrict__ src, const int* __restrict__ dst,
                        const int* __restrict__ offs, int* __restrict__ cursor, int* __restrict__ csr){
  int e = blockIdx.x*256 + threadIdx.x;
  if (e < NE){
    int d = dst[e];
    int p = atomicAdd(&cursor[d], 1);
    csr[offs[d]+p] = src[e];
  }
}

// ---------------- fold gf into first-layer biases ----------------
// b1eff layout: [0:128) emb, [(1+l)*128) msg layer l, [(7+l)*128) upd layer l

__global__ void k_biasfold(const float* __restrict__ dom, const float* __restrict__ tt,
                           const float* __restrict__ xg, const float* __restrict__ domn,
                           const float* __restrict__ tn,
                           const float* __restrict__ embW1, const float* __restrict__ embB1,
                           const float* __restrict__ msgW1, const float* __restrict__ msgB1,
                           const float* __restrict__ updW1, const float* __restrict__ updB1,
                           float* __restrict__ b1eff){
  float gf[12];
  gf[0]=dom[0]; gf[1]=dom[1]; gf[2]=dom[2]; gf[3]=tt[0];
  gf[4]=xg[0]; gf[5]=xg[1]; gf[6]=xg[2]; gf[7]=xg[3];
  gf[8]=domn[0]; gf[9]=domn[1]; gf[10]=domn[2]; gf[11]=tn[0];
  int b = blockIdx.x, t = threadIdx.x;
  if (b==0){
    float s = embB1[t];
    #pragma unroll
    for (int k=0;k<12;++k) s += gf[k]*embW1[(7+k)*HD + t];
    b1eff[t] = s;
  } else if (b<=6){
    int l=b-1;
    float s = msgB1[l*HD+t];
    #pragma unroll
    for (int k=0;k<12;++k) s += gf[k]*msgW1[((size_t)l*157 + 145+k)*HD + t];
    b1eff[(1+l)*HD + t] = s;
  } else {
    int l=b-7;
    float s = updB1[l*HD+t];
    #pragma unroll
    for (int k=0;k<12;++k) s += gf[k]*updW1[((size_t)l*268 + 256+k)*HD + t];
    b1eff[(7+l)*HD + t] = s;
  }
}

// ---------------- embedding: h = mlp2_relu([r,v,gf]) ----------------

__global__ void k_embed(const float* __restrict__ r, const float* __restrict__ v,
                        const float* __restrict__ W1, const float* __restrict__ b1e,
                        const float* __restrict__ W2, const float* __restrict__ b2,
                        float* __restrict__ h){
  __shared__ alignas(16) float a1s[4][HD];
  int tid=threadIdx.x, wid=tid>>6, lane=tid&63;
  int gw = blockIdx.x*4 + wid;
  int f0=lane, f1=lane+64;
  float* a1 = a1s[wid];
  float b1f0=b1e[f0], b1f1=b1e[f1], b2f0=b2[f0], b2f1=b2[f1];
  for (int n=gw*4; n<gw*4+4; ++n){
    float in7[7];
    in7[0]=r[n];
    #pragma unroll
    for (int k=0;k<6;++k) in7[1+k]=v[n*6+k];
    float z0=b1f0, z1=b1f1;
    #pragma unroll
    for (int k=0;k<7;++k){ z0 += in7[k]*W1[k*HD+f0]; z1 += in7[k]*W1[k*HD+f1]; }
    a1[f0]=relu_(z0); a1[f1]=relu_(z1);   // wave-private LDS, same-wave ordering
    float h0=b2f0, h1=b2f1;
    for (int k=0;k<HD;++k){ float a=a1[k]; h0+=a*W2[k*HD+f0]; h1+=a*W2[k*HD+f1]; }
    h[n*HD+f0]=relu_(h0); h[n*HD+f1]=relu_(h1);
  }
}

// ---------------- hW = h @ msg_W1[rows 0:128] ----------------

__global__ void k_hW(const float* __restrict__ h, const float* __restrict__ W, float* __restrict__ hW){
  __shared__ alignas(16) float hs[4][HD*4];
  int tid=threadIdx.x, wid=tid>>6, lane=tid&63;
  int gw=blockIdx.x*4+wid;
  int f0=lane, f1=lane+64;
  float* h4 = hs[wid];
  int n0 = gw*4;
  float4 hv0, hv1;
  hv0.x=h[(n0+0)*HD+f0]; hv0.y=h[(n0+1)*HD+f0]; hv0.z=h[(n0+2)*HD+f0]; hv0.w=h[(n0+3)*HD+f0];
  hv1.x=h[(n0+0)*HD+f1]; hv1.y=h[(n0+1)*HD+f1]; hv1.z=h[(n0+2)*HD+f1]; hv1.w=h[(n0+3)*HD+f1];
  *(float4*)&h4[f0*4]=hv0; *(float4*)&h4[f1*4]=hv1;
  float m0[4]={0,0,0,0}, m1[4]={0,0,0,0};
  for (int k=0;k<HD;++k){
    float4 a = *(const float4*)&h4[k*4];
    float w0=W[k*HD+f0], w1=W[k*HD+f1];
    m0[0]+=a.x*w0; m1[0]+=a.x*w1;
    m0[1]+=a.y*w0; m1[1]+=a.y*w1;
    m0[2]+=a.z*w0; m1[2]+=a.z*w1;
    m0[3]+=a.w*w0; m1[3]+=a.w*w1;
  }
  #pragma unroll
  for (int e=0;e<4;++e){ hW[(n0+e)*HD+f0]=m0[e]; hW[(n0+e)*HD+f1]=m1[e]; }
}

// ---------------- edge message MLP + per-node aggregation ----------------

__global__ __launch_bounds__(256) void k_edge(
    const float* __restrict__ hW, const float* __restrict__ v, const float* __restrict__ r,
    const float* __restrict__ pos, const float* __restrict__ dom,
    const int* __restrict__ offs, const int* __restrict__ csr,
    const float* __restrict__ W1r, const float* __restrict__ b1e,
    const float* __restrict__ W2, const float* __restrict__ b2,
    const float* __restrict__ invc, float* __restrict__ agg,
    float* __restrict__ zsum, float* __restrict__ zsumsq){
  __shared__ alignas(16) float W2s[HD*HD];
  __shared__ alignas(16) float a1s[4][HD*4];
  int tid=threadIdx.x;
  if (blockIdx.x==0 && tid<HD){ zsum[tid]=0.f; zsumsq[tid]=0.f; }  // zero stats for the upcoming upd
  for (int i=tid*4; i<HD*HD; i+=1024) *(float4*)&W2s[i] = *(const float4*)&W2[i];
  __syncthreads();
  int wid=tid>>6, lane=tid&63;
  int gw=blockIdx.x*4+wid;
  int f0=lane, f1=lane+64;
  float* a1p=a1s[wid];
  float b1f0=b1e[f0], b1f1=b1e[f1], b2f0=b2[f0], b2f1=b2[f1];
  float d0=dom[0], d1=dom[1], d2=dom[2];
  for (int n=gw*4; n<gw*4+4; ++n){
    float hwn0=hW[n*HD+f0], hwn1=hW[n*HD+f1];
    float vn0=v[n*6+0],vn1=v[n*6+1],vn2=v[n*6+2],vn3=v[n*6+3],vn4=v[n*6+4],vn5=v[n*6+5];
    float rn=r[n];
    float pn0=pos[n*3+0],pn1=pos[n*3+1],pn2=pos[n*3+2];
    float acc0=0.f, acc1=0.f;
    int ib=offs[n], ie=offs[n+1];
    for (int i0=ib; i0<ie; i0+=4){
      int cnt = ie - i0;
      float za0[4], za1[4];
      #pragma unroll
      for (int e=0;e<4;++e){
        int idx = (e<cnt)? (i0+e) : i0;
        int s = csr[idx];
        float feat[17];
        feat[0]=vn0; feat[1]=vn1; feat[2]=vn2; feat[3]=vn3; feat[4]=vn4; feat[5]=vn5;
        feat[6]=v[s*6+0]; feat[7]=v[s*6+1]; feat[8]=v[s*6+2];
        feat[9]=v[s*6+3]; feat[10]=v[s*6+4]; feat[11]=v[s*6+5];
        feat[12]=rn; feat[13]=r[s];
        {
          float xi,xj,diff,sh,ds;
          xi=pn0; xj=pos[s*3+0]; diff=xi-xj; sh=(xi<xj)?-d0:d0; ds=diff-sh; feat[14]=(fabsf(diff)<fabsf(ds))?diff:ds;
          xi=pn1; xj=pos[s*3+1]; diff=xi-xj; sh=(xi<xj)?-d1:d1; ds=diff-sh; feat[15]=(fabsf(diff)<fabsf(ds))?diff:ds;
          xi=pn2; xj=pos[s*3+2]; diff=xi-xj; sh=(xi<xj)?-d2:d2; ds=diff-sh; feat[16]=(fabsf(diff)<fabsf(ds))?diff:ds;
        }
        float z0 = hwn0 - hW[s*HD+f0] + b1f0;
        float z1 = hwn1 - hW[s*HD+f1] + b1f1;
        #pragma unroll
        for (int k=0;k<17;++k){ z0 += feat[k]*W1r[k*HD+f0]; z1 += feat[k]*W1r[k*HD+f1]; }
        za0[e]=relu_(z0); za1[e]=relu_(z1);
      }
      *(float4*)&a1p[f0*4] = make_float4(za0[0],za0[1],za0[2],za0[3]);
      *(float4*)&a1p[f1*4] = make_float4(za1[0],za1[1],za1[2],za1[3]);
      float m00=b2f0,m01=b2f1,m10=b2f0,m11=b2f1,m20=b2f0,m21=b2f1,m30=b2f0,m31=b2f1;
      for (int k=0;k<HD;++k){
        float4 a = *(const float4*)&a1p[k*4];
        float w0=W2s[k*HD+f0], w1=W2s[k*HD+f1];
        m00+=a.x*w0; m01+=a.x*w1;
        m10+=a.y*w0; m11+=a.y*w1;
        m20+=a.z*w0; m21+=a.z*w1;
        m30+=a.w*w0; m31+=a.w*w1;
      }
      acc0+=relu_(m00); acc1+=relu_(m01);
      if (cnt>1){acc0+=relu_(m10); acc1+=relu_(m11);}
      if (cnt>2){acc0+=relu_(m20); acc1+=relu_(m21);}
      if (cnt>3){acc0+=relu_(m30); acc1+=relu_(m31);}
    }
    float ic=invc[n];
    agg[n*HD+f0]=acc0*ic; agg[n*HD+f1]=acc1*ic;   // inv_counts applied HERE (only here)
  }
}

// ---------------- update MLP + residual + stats partials ----------------

__global__ void k_upd(const float* __restrict__ h, const float* __restrict__ agg,
                      const float* __restrict__ U1, const float* __restrict__ b1e,
                      const float* __restrict__ U2, const float* __restrict__ b2,
                      float* __restrict__ hb, float* __restrict__ sum, float* __restrict__ sumsq){
  __shared__ alignas(16) float xs[4][2*HD*4];
  __shared__ alignas(16) float a1s[4][HD*4];
  int tid=threadIdx.x, wid=tid>>6, lane=tid&63;
  int gw=blockIdx.x*4+wid;
  int f0=lane, f1=lane+64;
  float* x4=xs[wid];
  float* a1p=a1s[wid];
  int n0=gw*4;
  float4 hv0,hv1,av0,av1;
  hv0.x=h[(n0+0)*HD+f0]; hv0.y=h[(n0+1)*HD+f0]; hv0.z=h[(n0+2)*HD+f0]; hv0.w=h[(n0+3)*HD+f0];
  hv1.x=h[(n0+0)*HD+f1]; hv1.y=h[(n0+1)*HD+f1]; hv1.z=h[(n0+2)*HD+f1]; hv1.w=h[(n0+3)*HD+f1];
  av0.x=agg[(n0+0)*HD+f0]; av0.y=agg[(n0+1)*HD+f0]; av0.z=agg[(n0+2)*HD+f0]; av0.w=agg[(n0+3)*HD+f0];
  av1.x=agg[(n0+0)*HD+f1]; av1.y=agg[(n0+1)*HD+f1]; av1.z=agg[(n0+2)*HD+f1]; av1.w=agg[(n0+3)*HD+f1];
  *(float4*)&x4[f0*4]=hv0; *(float4*)&x4[f1*4]=hv1;
  *(float4*)&x4[(HD+f0)*4]=av0; *(float4*)&x4[(HD+f1)*4]=av1;
  float b1f0=b1e[f0], b1f1=b1e[f1];
  float zf0[4]={b1f0,b1f0,b1f0,b1f0}, zf1[4]={b1f1,b1f1,b1f1,b1f1};
  for (int k=0;k<2*HD;++k){
    float4 a = *(const float4*)&x4[k*4];
    float w0=U1[k*HD+f0], w1=U1[k*HD+f1];
    zf0[0]+=a.x*w0; zf1[0]+=a.x*w1;
    zf0[1]+=a.y*w0; zf1[1]+=a.y*w1;
    zf0[2]+=a.z*w0; zf1[2]+=a.z*w1;
    zf0[3]+=a.w*w0; zf1[3]+=a.w*w1;
  }
  *(float4*)&a1p[f0*4] = make_float4(relu_(zf0[0]),relu_(zf0[1]),relu_(zf0[2]),relu_(zf0[3]));
  *(float4*)&a1p[f1*4] = make_float4(relu_(zf1[0]),relu_(zf1[1]),relu_(zf1[2]),relu_(zf1[3]));
  float b2f0=b2[f0], b2f1=b2[f1];
  float uf0[4]={b2f0,b2f0,b2f0,b2f0}, uf1[4]={b2f1,b2f1,b2f1,b2f1};
  for (int k=0;k<HD;++k){
    float4 a = *(const float4*)&a1p[k*4];
    float w0=U2[k*HD+f0], w1=U2[k*HD+f1];
    uf0[0]+=a.x*w0; uf1[0]+=a.x*w1;
    uf0[1]+=a.y*w0; uf1[1]+=a.y*w1;
    uf0[2]+=a.z*w0; uf1[2]+=a.z*w1;
    uf0[3]+=a.w*w0; uf1[3]+=a.w*w1;
  }
  float hvs0[4]={hv0.x,hv0.y,hv0.z,hv0.w};
  float hvs1[4]={hv1.x,hv1.y,hv1.z,hv1.w};
  float s0=0,q0=0,s1=0,q1=0;
  #pragma unroll
  for (int e=0;e<4;++e){
    float b0 = hvs0[e] + relu_(uf0[e]);
    float b1v = hvs1[e] + relu_(uf1[e]);
    hb[(n0+e)*HD+f0]=b0; hb[(n0+e)*HD+f1]=b1v;
    s0+=b0; q0+=b0*b0; s1+=b1v; q1+=b1v*b1v;
  }
  atomicAdd(&sum[f0], s0); atomicAdd(&sumsq[f0], q0);
  atomicAdd(&sum[f1], s1); atomicAdd(&sumsq[f1], q1);
}

__global__ void k_normfin(const float* __restrict__ sum, const float* __restrict__ sumsq,
                          float* __restrict__ mu, float* __restrict__ rstd){
  int t=threadIdx.x;
  float m = sum[t]*(1.0f/NN);
  float var = sumsq[t]*(1.0f/NN) - m*m;
  mu[t]=m;
  rstd[t]=rsqrtf(fmaxf(var,0.0f)+EPSV);
}

__global__ void k_normalize(const float* __restrict__ hb, const float* __restrict__ mu,
                            const float* __restrict__ rstd, float* __restrict__ h){
  int i = blockIdx.x*256 + threadIdx.x;
  int f = i & (HD-1);
  h[i] = (hb[i]-mu[f])*rstd[f];
}

__global__ void k_colsum(const float* __restrict__ h, float* __restrict__ hsum){
  int f=threadIdx.x;
  float s=0.f;
  for (int n=blockIdx.x; n<NN; n+=100) s += h[n*HD+f];
  atomicAdd(&hsum[f], s);
}

// ---------------- decoder + outputs ----------------

__global__ void k_out(const float* __restrict__ h, const float* __restrict__ pos, const float* __restrict__ v,
                      const float* __restrict__ W1, const float* __restrict__ b1,
                      const float* __restrict__ W2, const float* __restrict__ b2,
                      const float* __restrict__ domn, float* __restrict__ out){
  __shared__ alignas(16) float hs[4][HD*4];
  __shared__ alignas(16) float a1s[4][HD*4];
  int tid=threadIdx.x, wid=tid>>6, lane=tid&63;
  int gw=blockIdx.x*4+wid;
  int f0=lane, f1=lane+64;
  float* h4=hs[wid];
  float* a1p=a1s[wid];
  int n0=gw*4;
  float4 hv0,hv1;
  hv0.x=h[(n0+0)*HD+f0]; hv0.y=h[(n0+1)*HD+f0]; hv0.z=h[(n0+2)*HD+f0]; hv0.w=h[(n0+3)*HD+f0];
  hv1.x=h[(n0+0)*HD+f1]; hv1.y=h[(n0+1)*HD+f1]; hv1.z=h[(n0+2)*HD+f1]; hv1.w=h[(n0+3)*HD+f1];
  *(float4*)&h4[f0*4]=hv0; *(float4*)&h4[f1*4]=hv1;
  float b1f0=b1[f0], b1f1=b1[f1];
  float zf0[4]={b1f0,b1f0,b1f0,b1f0}, zf1[4]={b1f1,b1f1,b1f1,b1f1};
  for (int k=0;k<HD;++k){
    float4 a = *(const float4*)&h4[k*4];
    float w0=W1[k*HD+f0], w1=W1[k*HD+f1];
    zf0[0]+=a.x*w0; zf1[0]+=a.x*w1;
    zf0[1]+=a.y*w0; zf1[1]+=a.y*w1;
    zf0[2]+=a.z*w0; zf1[2]+=a.z*w1;
    zf0[3]+=a.w*w0; zf1[3]+=a.w*w1;
  }
  *(float4*)&a1p[f0*4] = make_float4(relu_(zf0[0]),relu_(zf0[1]),relu_(zf0[2]),relu_(zf0[3]));
  *(float4*)&a1p[f1*4] = make_float4(relu_(zf1[0]),relu_(zf1[1]),relu_(zf1[2]),relu_(zf1[3]));
  if (lane < 36){
    int e = lane/9, j = lane - e*9;
    int n = n0+e;
    float p = b2[j];
    for (int k=0;k<HD;++k) p += a1p[k*4+e]*W2[k*9+j];
    if (j<3){
      p += pos[n*3+j];
      float d = domn[j];
      p = p - floorf(p/d)*d;
      out[n*3+j] = p;
    } else {
      p += v[n*6 + (j-3)];
      out[3*NN + n*6 + (j-3)] = p;
    }
  }
}

__global__ void k_macro(const float* __restrict__ hsum,
                        const float* __restrict__ W1, const float* __restrict__ b1,
                        const float* __restrict__ W2, const float* __restrict__ b2,
                        float* __restrict__ out){
  __shared__ float hm[HD];
  __shared__ float as[HD];
  int t=threadIdx.x;
  hm[t] = hsum[t]*(1.0f/NN);
  __syncthreads();
  float z=b1[t];
  for (int k=0;k<HD;++k) z += hm[k]*W1[k*HD+t];
  as[t]=relu_(z);
  __syncthreads();
  if (t<3){
    float p=b2[t];
    for (int k=0;k<HD;++k) p += as[k]*W2[k*3+t];
    out[9*NN+t]=p;
  }
}

// ---------------- host launch ----------------

extern "C" void kernel_launch(void* const* d_in, const int* in_sizes, int n_in,
                              void* d_out, int out_size, void* d_ws, size_t ws_size,
                              hipStream_t stream) {
  const float* v    = (const float*)d_in[0];
  const float* pos  = (const float*)d_in[1];
  const float* r    = (const float*)d_in[2];
  const float* dom  = (const float*)d_in[3];
  const float* tt   = (const float*)d_in[4];
  const float* xg   = (const float*)d_in[5];
  const float* domn = (const float*)d_in[6];
  const float* tn   = (const float*)d_in[7];
  const int*   eidx = (const int*)d_in[8];
  const float* embW1 = (const float*)d_in[10];
  const float* embB1 = (const float*)d_in[11];
  const float* embW2 = (const float*)d_in[12];
  const float* embB2 = (const float*)d_in[13];
  const float* msgW1 = (const float*)d_in[14];
  const float* msgB1 = (const float*)d_in[15];
  const float* msgW2 = (const float*)d_in[16];
  const float* msgB2 = (const float*)d_in[17];
  const float* updW1 = (const float*)d_in[18];
  const float* updB1 = (const float*)d_in[19];
  const float* updW2 = (const float*)d_in[20];
  const float* updB2 = (const float*)d_in[21];
  const float* outW1 = (const float*)d_in[22];
  const float* outB1 = (const float*)d_in[23];
  const float* outW2 = (const float*)d_in[24];
  const float* outB2 = (const float*)d_in[25];
  const float* macW1 = (const float*)d_in[26];
  const float* macB1 = (const float*)d_in[27];
  const float* macW2 = (const float*)d_in[28];
  const float* macB2 = (const float*)d_in[29];
  float* out = (float*)d_out;
  float* ws  = (float*)d_ws;

  float* h     = ws;
  float* hW    = ws + 1280000;
  float* agg   = ws + 2560000;
  float* hb    = ws + 3840000;
  float* invc  = ws + 5120000;
  float* b1eff = ws + 5130000;   // 13*128
  float* sum   = ws + 5131664;
  float* sumsq = ws + 5131792;
  float* mu    = ws + 5131920;
  float* rstd  = ws + 5132048;
  float* hsum  = ws + 5132176;
  int* counts  = (int*)(ws + 5132304);
  int* offs    = counts + NN;       // NN+1
  int* cursor  = offs + NN + 1;
  int* csr     = cursor + NN;       // NE

  const int* srcA = eidx;
  const int* dstA = eidx + NE;

  hipMemsetAsync(counts, 0, NN*sizeof(int), stream);
  hipMemsetAsync(cursor, 0, NN*sizeof(int), stream);
  hipMemsetAsync(hsum, 0, HD*sizeof(float), stream);

  k_degree<<<(NE+255)/256, 256, 0, stream>>>(dstA, counts);
  k_scan<<<1, 1024, 0, stream>>>(counts, offs, invc);
  k_place<<<(NE+255)/256, 256, 0, stream>>>(srcA, dstA, offs, cursor, csr);
  k_biasfold<<<13, 128, 0, stream>>>(dom, tt, xg, domn, tn, embW1, embB1, msgW1, msgB1, updW1, updB1, b1eff);
  k_embed<<<625, 256, 0, stream>>>(r, v, embW1, b1eff, embW2, embB2, h);

  for (int l=0; l<NL; ++l){
    k_hW<<<625,256,0,stream>>>(h, msgW1 + (size_t)l*157*HD, hW);
    k_edge<<<625,256,0,stream>>>(hW, v, r, pos, dom, offs, csr,
        msgW1 + ((size_t)l*157+128)*HD, b1eff + (1+l)*HD,
        msgW2 + (size_t)l*HD*HD, msgB2 + l*HD, invc, agg, sum, sumsq);
    k_upd<<<625,256,0,stream>>>(h, agg,
        updW1 + (size_t)l*268*HD, b1eff + (7+l)*HD,
        updW2 + (size_t)l*HD*HD, updB2 + l*HD, hb, sum, sumsq);
    k_normfin<<<1,128,0,stream>>>(sum, sumsq, mu, rstd);
    k_normalize<<<5000,256,0,stream>>>(hb, mu, rstd, h);
  }

  k_colsum<<<100,128,0,stream>>>(h, hsum);
  k_out<<<625,256,0,stream>>>(h, pos, v, outW1, outB1, outW2, outB2, domn, out);
  k_macro<<<1,128,0,stream>>>(hsum, macW1, macB1, macW2, macB2, out);
}